// Round 9
// baseline (360.590 us; speedup 1.0000x reference)
//
#include <hip/hip_runtime.h>

typedef __bf16 bf16_t;
typedef __bf16 v8bf __attribute__((ext_vector_type(8)));
typedef __bf16 v4bf __attribute__((ext_vector_type(4)));
typedef float  v4f  __attribute__((ext_vector_type(4)));

#define D_MODEL 1024
#define NHEAD   16
#define DHEAD   64
#define SEQ     2048
#define BATCH   4
#define ROWS    (BATCH*SEQ)   // 8192

// async global->LDS, 16B per lane; LDS dest = wave-uniform base + lane*16
#define GLD16(g, l) __builtin_amdgcn_global_load_lds( \
    (const __attribute__((address_space(1))) void*)(g), \
    (__attribute__((address_space(3))) void*)(l), 16, 0, 0)

// ---------------------------------------------------------------- fused prep (casts + bias pack)
__global__ __launch_bounds__(256) void k_prep(const float* __restrict__ batch,
                                              const float* __restrict__ wq,
                                              const float* __restrict__ wk,
                                              const float* __restrict__ wv,
                                              const float* __restrict__ wo,
                                              const float* __restrict__ bq,
                                              const float* __restrict__ bk,
                                              const float* __restrict__ bv,
                                              bf16_t* __restrict__ Xb,
                                              bf16_t* __restrict__ Wqkv,
                                              bf16_t* __restrict__ Wob,
                                              float* __restrict__ bqkv) {
    int bid = blockIdx.x, t = threadIdx.x;
    const float* src; bf16_t* dst; int idx;
    if (bid < 8192)       { src = batch; dst = Xb;             idx = bid * 256 + t; }
    else if (bid < 9216)  { src = wq;    dst = Wqkv;           idx = (bid - 8192) * 256 + t; }
    else if (bid < 10240) { src = wk;    dst = Wqkv + 1048576; idx = (bid - 9216) * 256 + t; }
    else if (bid < 11264) { src = wv;    dst = Wqkv + 2097152; idx = (bid - 10240) * 256 + t; }
    else if (bid < 12288) { src = wo;    dst = Wob;            idx = (bid - 11264) * 256 + t; }
    else {
        int i = (bid - 12288) * 256 + t;   // 0..3071
        if (i < 1024) bqkv[i] = bq[i];
        else if (i < 2048) bqkv[i] = bk[i - 1024];
        else if (i < 3072) bqkv[i] = bv[i - 2048];
        return;
    }
    float4 f = ((const float4*)src)[idx];
    v4bf o;
    o[0] = (bf16_t)f.x; o[1] = (bf16_t)f.y; o[2] = (bf16_t)f.z; o[3] = (bf16_t)f.w;
    ((v4bf*)dst)[idx] = o;
}

// ---------------------------------------------------------------- GEMM  C = A * B^T (+bias) (+resid)
// global_load_lds staging, double-buffered LDS, ONE barrier per K-iter.
// Unpadded 128x32 tiles, XOR swizzle (row r: logical chunk c at phys c^((r>>1)&3)).
__global__ __launch_bounds__(256, 3) void k_gemm_bt(
    const bf16_t* __restrict__ A, const bf16_t* __restrict__ Bm,
    const float* __restrict__ bias, const float* __restrict__ resid,
    bf16_t* __restrict__ Cb, float* __restrict__ Cf,
    int M, int N, int K, int qcols, float qmul)
{
    __shared__ bf16_t As[2][128 * 32];
    __shared__ bf16_t Bs[2][128 * 32];

    int nTile = N >> 7;
    int m0 = (blockIdx.x / nTile) << 7;
    int n0 = (blockIdx.x % nTile) << 7;
    int t = threadIdx.x;
    int w = t >> 6, lane = t & 63, quad = lane >> 4, ln = lane & 15;
    int wm = (w >> 1) << 6, wn = (w & 1) << 6;

    int srow = lane >> 2;                               // 0..15
    int scol = ((lane & 3) ^ ((lane >> 3) & 3)) << 3;   // swizzled logical chunk *8
    const bf16_t* Ag0 = A  + (size_t)(m0 + w * 16 +      srow) * K + scol;
    const bf16_t* Ag1 = A  + (size_t)(m0 + w * 16 + 64 + srow) * K + scol;
    const bf16_t* Bg0 = Bm + (size_t)(n0 + w * 16 +      srow) * K + scol;
    const bf16_t* Bg1 = Bm + (size_t)(n0 + w * 16 + 64 + srow) * K + scol;
    int lo0 = (w * 16) * 32, lo1 = (w * 16 + 64) * 32;

    v4f acc[4][4];
#pragma unroll
    for (int i = 0; i < 4; i++)
#pragma unroll
        for (int j = 0; j < 4; j++) acc[i][j] = (v4f){0.f, 0.f, 0.f, 0.f};

    // prologue: tile 0 -> buf 0
    GLD16(Ag0, &As[0][lo0]);
    GLD16(Ag1, &As[0][lo1]);
    GLD16(Bg0, &Bs[0][lo0]);
    GLD16(Bg1, &Bs[0][lo1]);

    int sw = (ln >> 1) & 3;   // read-side swizzle
    int buf = 0;
    for (int k0 = 0; k0 < K; k0 += 32, buf ^= 1) {
        __syncthreads();   // vmcnt(0) drain covers tile-k0 loads (in flight since k0-32)
        if (k0 + 32 < K) {
            GLD16(Ag0 + k0 + 32, &As[buf ^ 1][lo0]);
            GLD16(Ag1 + k0 + 32, &As[buf ^ 1][lo1]);
            GLD16(Bg0 + k0 + 32, &Bs[buf ^ 1][lo0]);
            GLD16(Bg1 + k0 + 32, &Bs[buf ^ 1][lo1]);
        }
        v8bf af[4], bfr[4];
#pragma unroll
        for (int mt = 0; mt < 4; mt++)
            af[mt] = *(const v8bf*)&As[buf][(wm + mt * 16 + ln) * 32 + ((quad ^ sw) << 3)];
#pragma unroll
        for (int nt = 0; nt < 4; nt++)
            bfr[nt] = *(const v8bf*)&Bs[buf][(wn + nt * 16 + ln) * 32 + ((quad ^ sw) << 3)];
#pragma unroll
        for (int mt = 0; mt < 4; mt++)
#pragma unroll
            for (int nt = 0; nt < 4; nt++)
                acc[mt][nt] = __builtin_amdgcn_mfma_f32_16x16x32_bf16(af[mt], bfr[nt], acc[mt][nt], 0, 0, 0);
    }

#pragma unroll
    for (int mt = 0; mt < 4; mt++) {
#pragma unroll
        for (int r = 0; r < 4; r++) {
            int row = m0 + wm + mt * 16 + quad * 4 + r;
#pragma unroll
            for (int nt = 0; nt < 4; nt++) {
                int col = n0 + wn + nt * 16 + ln;
                float v = acc[mt][nt][r] + bias[col];
                if (Cf) Cf[(size_t)row * N + col] = v + resid[(size_t)row * N + col];
                else {
                    if (col < qcols) v *= qmul;
                    Cb[(size_t)row * N + col] = (bf16_t)v;
                }
            }
        }
    }
}

// ---------------------------------------------------------------- V transpose: qkv V-cols -> Vt[bh][d][s]
__global__ __launch_bounds__(256) void k_transpose_v(const bf16_t* __restrict__ qkv,
                                                     bf16_t* __restrict__ vt) {
    __shared__ bf16_t tile[64 * 72];
    int bid = blockIdx.x;
    int st = bid & 31, bh = bid >> 5, b = bh >> 4, h = bh & 15;
    int t = threadIdx.x;
    const bf16_t* src = qkv + (size_t)(b * SEQ + st * 64) * 3072 + 2048 + h * 64;
#pragma unroll
    for (int i = 0; i < 2; i++) {
        int c = t + i * 256, row = c >> 3, c8 = (c & 7) << 3;
        *(uint4*)&tile[row * 72 + c8] = *(const uint4*)(src + (size_t)row * 3072 + c8);
    }
    __syncthreads();
    bf16_t* dst = vt + (size_t)bh * DHEAD * SEQ + st * 64;
#pragma unroll
    for (int i = 0; i < 2; i++) {
        int c = t + i * 256, d = c >> 3, s8 = (c & 7) << 3;
        v8bf o;
#pragma unroll
        for (int j = 0; j < 8; j++) o[j] = tile[(s8 + j) * 72 + d];
        *(v8bf*)(dst + (size_t)d * SEQ + s8) = o;
    }
}

// ---------------------------------------------------------------- attention
// grid: B*H*(S/256) = 512 blocks (2/CU exact), 256 thr; wave owns 64 q-rows
// (4 q-sets of 16). K/V double-buffered 64x64 LDS tiles via global_load_lds,
// XOR swizzle chunk^(row&7), one barrier/iter. QK keys PERMUTED per n-tile
// (key = 4*ln + nt) so each lane's 4 probs are contiguous -> P written as ONE
// ds_write_b64 per r (4/qs, was 16 scalar b16). P layout: elem (m,s) at
// m*64 + (((s>>3)^(m&7))<<3) + (s&7) -> optimal-round writes AND b128 reads.
// PV reads P in natural A-layout (key order preserved by addressed writes).
// launch_bounds(256,1): VGPR cap 256 (~220 live; (256,2+) caps at 512/(2w)
// and spills -- round-7 lesson). Raw v_exp_f32; denominator deferred.
__global__ __launch_bounds__(256, 1) void k_attn(const bf16_t* __restrict__ qkv,
                                                 const bf16_t* __restrict__ vt,
                                                 bf16_t* __restrict__ attn) {
    __shared__ bf16_t Ks[2][64 * 64];
    __shared__ bf16_t Vs[2][64 * 64];
    __shared__ bf16_t Pl[4][16 * 64];

    int bid = blockIdx.x;
    int qt = bid & 7, bh = bid >> 3, b = bh >> 4, h = bh & 15;
    int t = threadIdx.x, w = t >> 6, lane = t & 63, quad = lane >> 4, ln = lane & 15;
    int q0 = qt * 256 + w * 64;

    v8bf qf[4][2];
#pragma unroll
    for (int qs = 0; qs < 4; qs++) {
        const bf16_t* Qp = qkv + (size_t)(b * SEQ + q0 + qs * 16 + ln) * 3072 + h * 64 + quad * 8;
        qf[qs][0] = *(const v8bf*)Qp;
        qf[qs][1] = *(const v8bf*)(Qp + 32);
    }

    // staging addresses: wave w instr i covers rows (w+4i)*8 .. +7
    int srow = lane >> 3;                        // 0..7
    int scol = ((lane & 7) ^ (lane >> 3)) << 3;  // swizzled logical chunk *8
    const bf16_t* Kg0 = qkv + (size_t)(b * SEQ + w * 8 +      srow) * 3072 + 1024 + h * 64 + scol;
    const bf16_t* Kg1 = qkv + (size_t)(b * SEQ + w * 8 + 32 + srow) * 3072 + 1024 + h * 64 + scol;
    const bf16_t* Vg0 = vt + (size_t)bh * DHEAD * SEQ + (size_t)(w * 8 +      srow) * SEQ + scol;
    const bf16_t* Vg1 = vt + (size_t)bh * DHEAD * SEQ + (size_t)(w * 8 + 32 + srow) * SEQ + scol;
    int ko0 = (w * 8) * 64, ko1 = (w * 8 + 32) * 64;

    bf16_t* Pw = &Pl[w][0];
    int swv = ln & 7;   // read-side swizzle for V rows (row&7 = ln&7)

    v4f o[4][4];
#pragma unroll
    for (int qs = 0; qs < 4; qs++)
#pragma unroll
        for (int d = 0; d < 4; d++) o[qs][d] = (v4f){0.f, 0.f, 0.f, 0.f};
    float lsum[4][4];
#pragma unroll
    for (int qs = 0; qs < 4; qs++)
#pragma unroll
        for (int r = 0; r < 4; r++) lsum[qs][r] = 0.f;

    // prologue: tile 0 -> buf 0
    GLD16(Kg0, &Ks[0][ko0]);
    GLD16(Kg1, &Ks[0][ko1]);
    GLD16(Vg0, &Vs[0][ko0]);
    GLD16(Vg1, &Vs[0][ko1]);

    int buf = 0;
    for (int kt = 0; kt < SEQ; kt += 64, buf ^= 1) {
        __syncthreads();   // vmcnt(0) drain covers tile-kt loads (issued last iter)
        if (kt + 64 < SEQ) {
            GLD16(Kg0 + (size_t)(kt + 64) * 3072, &Ks[buf ^ 1][ko0]);
            GLD16(Kg1 + (size_t)(kt + 64) * 3072, &Ks[buf ^ 1][ko1]);
            GLD16(Vg0 + kt + 64, &Vs[buf ^ 1][ko0]);
            GLD16(Vg1 + kt + 64, &Vs[buf ^ 1][ko1]);
        }

        // QK^T, all 4 q-sets; keys permuted: n-tile nt, lane ln -> key 4*ln+nt
        v4f s[4][4];
#pragma unroll
        for (int nt = 0; nt < 4; nt++) {
            int rr = 4 * ln + nt;
            int swr = rr & 7;
            v8bf kf0 = *(const v8bf*)&Ks[buf][rr * 64 + ((quad ^ swr) << 3)];
            v8bf kf1 = *(const v8bf*)&Ks[buf][rr * 64 + (((quad + 4) ^ swr) << 3)];
#pragma unroll
            for (int qs = 0; qs < 4; qs++) {
                s[qs][nt] = (v4f){0.f, 0.f, 0.f, 0.f};
                s[qs][nt] = __builtin_amdgcn_mfma_f32_16x16x32_bf16(qf[qs][0], kf0, s[qs][nt], 0, 0, 0);
                s[qs][nt] = __builtin_amdgcn_mfma_f32_16x16x32_bf16(qf[qs][1], kf1, s[qs][nt], 0, 0, 0);
            }
        }

        // V fragments (shared by all q-sets)
        v8bf vf[8];
#pragma unroll
        for (int d = 0; d < 4; d++) {
            vf[d * 2]     = *(const v8bf*)&Vs[buf][(d * 16 + ln) * 64 + ((quad ^ swv) << 3)];
            vf[d * 2 + 1] = *(const v8bf*)&Vs[buf][(d * 16 + ln) * 64 + (((quad + 4) ^ swv) << 3)];
        }

        // per q-set: exp2 + packed P write (b64) -> PV (in-order DS queue
        // serializes each qs's reads after its writes, and the next qs's
        // writes after those reads)
#pragma unroll
        for (int qs = 0; qs < 4; qs++) {
#pragma unroll
            for (int r = 0; r < 4; r++) {
                float p0 = __builtin_amdgcn_exp2f(s[qs][0][r]);
                float p1 = __builtin_amdgcn_exp2f(s[qs][1][r]);
                float p2 = __builtin_amdgcn_exp2f(s[qs][2][r]);
                float p3 = __builtin_amdgcn_exp2f(s[qs][3][r]);
                int m = quad * 4 + r;
                v4bf pk;
                pk[0] = (bf16_t)p0; pk[1] = (bf16_t)p1;
                pk[2] = (bf16_t)p2; pk[3] = (bf16_t)p3;
                *(v4bf*)&Pw[m * 64 + (((ln >> 1) ^ (m & 7)) << 3) + ((ln & 1) << 2)] = pk;
                lsum[qs][r] += (p0 + p1) + (p2 + p3);
            }
#pragma unroll
            for (int tk = 0; tk < 2; tk++) {
                v8bf pf = *(const v8bf*)&Pw[ln * 64 + (((tk * 4 + quad) ^ (ln & 7)) << 3)];
#pragma unroll
                for (int d = 0; d < 4; d++)
                    o[qs][d] = __builtin_amdgcn_mfma_f32_16x16x32_bf16(pf, vf[tk + d * 2], o[qs][d], 0, 0, 0);
            }
        }
    }

#pragma unroll
    for (int qs = 0; qs < 4; qs++)
#pragma unroll
        for (int r = 0; r < 4; r++) {
#pragma unroll
            for (int off = 1; off < 16; off <<= 1) lsum[qs][r] += __shfl_xor(lsum[qs][r], off);
        }

#pragma unroll
    for (int qs = 0; qs < 4; qs++) {
        int rowg = b * SEQ + q0 + qs * 16;
#pragma unroll
        for (int r = 0; r < 4; r++) {
            float inv = 1.f / lsum[qs][r];
#pragma unroll
            for (int d = 0; d < 4; d++)
                attn[(size_t)(rowg + quad * 4 + r) * D_MODEL + h * 64 + d * 16 + ln] =
                    (bf16_t)(o[qs][d][r] * inv);
        }
    }
}

// ---------------------------------------------------------------- LayerNorm (one row / block)
__global__ __launch_bounds__(256) void k_layernorm(const float* __restrict__ y,
                                                   const float* __restrict__ g,
                                                   const float* __restrict__ beta,
                                                   float* __restrict__ out) {
    __shared__ float rs[4], rq[4];
    int row = blockIdx.x, t = threadIdx.x;
    int w = t >> 6, lane = t & 63;
    float4 v = ((const float4*)(y + (size_t)row * D_MODEL))[t];
    float s = v.x + v.y + v.z + v.w;
    float q = v.x * v.x + v.y * v.y + v.z * v.z + v.w * v.w;
#pragma unroll
    for (int off = 1; off < 64; off <<= 1) {
        s += __shfl_xor(s, off);
        q += __shfl_xor(q, off);
    }
    if (lane == 0) { rs[w] = s; rq[w] = q; }
    __syncthreads();
    s = rs[0] + rs[1] + rs[2] + rs[3];
    q = rq[0] + rq[1] + rq[2] + rq[3];
    float mu = s * (1.f / D_MODEL);
    float var = q * (1.f / D_MODEL) - mu * mu;
    float rstd = rsqrtf(var + 1e-5f);
    float4 gg = ((const float4*)g)[t];
    float4 bb = ((const float4*)beta)[t];
    float4 o;
    o.x = (v.x - mu) * rstd * gg.x + bb.x;
    o.y = (v.y - mu) * rstd * gg.y + bb.y;
    o.z = (v.z - mu) * rstd * gg.z + bb.z;
    o.w = (v.w - mu) * rstd * gg.w + bb.w;
    ((float4*)(out + (size_t)row * D_MODEL))[t] = o;
}

// ---------------------------------------------------------------- launch
extern "C" void kernel_launch(void* const* d_in, const int* in_sizes, int n_in,
                              void* d_out, int out_size, void* d_ws, size_t ws_size,
                              hipStream_t stream) {
    const float* batch = (const float*)d_in[0];
    const float* wq = (const float*)d_in[1];
    const float* bq = (const float*)d_in[2];
    const float* wk = (const float*)d_in[3];
    const float* bk = (const float*)d_in[4];
    const float* wv = (const float*)d_in[5];
    const float* bv = (const float*)d_in[6];
    const float* wo = (const float*)d_in[7];
    const float* bo = (const float*)d_in[8];
    const float* ln_g = (const float*)d_in[9];
    const float* ln_b = (const float*)d_in[10];
    float* out = (float*)d_out;

    char* ws = (char*)d_ws;
    size_t offXb   = 0;                                          // bf16 X (later Vt)
    size_t offWqkv = offXb + (size_t)ROWS * D_MODEL * 2;
    size_t offWo   = offWqkv + (size_t)3072 * 1024 * 2;
    size_t offBias = offWo + (size_t)1024 * 1024 * 2;
    size_t offQKV  = offBias + 3072 * 4;                         // bf16 qkv (later fp32 y)
    size_t offAttn = offQKV + (size_t)ROWS * 3072 * 2;
    size_t total   = offAttn + (size_t)ROWS * D_MODEL * 2;       // = 92,286,976
    if (ws_size < total) return;

    bf16_t* Xb   = (bf16_t*)(ws + offXb);
    bf16_t* Vt   = (bf16_t*)(ws + offXb);
    bf16_t* Wqkv = (bf16_t*)(ws + offWqkv);
    bf16_t* Wob  = (bf16_t*)(ws + offWo);
    float*  bqkv = (float*)(ws + offBias);
    bf16_t* qkv  = (bf16_t*)(ws + offQKV);
    float*  y    = (float*)(ws + offQKV);
    bf16_t* attn = (bf16_t*)(ws + offAttn);

    const float SC = 0.125f * 1.44269504088896f;  // 1/sqrt(64) * log2(e), folded into Q

    k_prep<<<12300, 256, 0, stream>>>(batch, wq, wk, wv, wo, bq, bk, bv,
                                      Xb, Wqkv, Wob, bqkv);
    k_gemm_bt<<<64 * 24, 256, 0, stream>>>(Xb, Wqkv, bqkv, nullptr, qkv, nullptr,
                                           8192, 3072, 1024, 1024, SC);
    k_transpose_v<<<2048, 256, 0, stream>>>(qkv, Vt);
    k_attn<<<512, 256, 0, stream>>>(qkv, Vt, attn);
    k_gemm_bt<<<64 * 8, 256, 0, stream>>>(attn, Wob, bo, batch, nullptr, y,
                                          8192, 1024, 1024, 0, 1.0f);
    k_layernorm<<<8192, 256, 0, stream>>>(y, ln_g, ln_b, out);
}

// Round 10
// 340.182 us; speedup vs baseline: 1.0600x; 1.0600x over previous
//
#include <hip/hip_runtime.h>

typedef __bf16 bf16_t;
typedef __bf16 v8bf __attribute__((ext_vector_type(8)));
typedef __bf16 v4bf __attribute__((ext_vector_type(4)));
typedef float  v4f  __attribute__((ext_vector_type(4)));

#define D_MODEL 1024
#define NHEAD   16
#define DHEAD   64
#define SEQ     2048
#define BATCH   4
#define ROWS    (BATCH*SEQ)   // 8192

// async global->LDS, 16B per lane; LDS dest = wave-uniform base + lane*16
#define GLD16(g, l) __builtin_amdgcn_global_load_lds( \
    (const __attribute__((address_space(1))) void*)(g), \
    (__attribute__((address_space(3))) void*)(l), 16, 0, 0)

// ---------------------------------------------------------------- fused prep (casts + bias pack)
__global__ __launch_bounds__(256) void k_prep(const float* __restrict__ batch,
                                              const float* __restrict__ wq,
                                              const float* __restrict__ wk,
                                              const float* __restrict__ wv,
                                              const float* __restrict__ wo,
                                              const float* __restrict__ bq,
                                              const float* __restrict__ bk,
                                              const float* __restrict__ bv,
                                              bf16_t* __restrict__ Xb,
                                              bf16_t* __restrict__ Wqkv,
                                              bf16_t* __restrict__ Wob,
                                              float* __restrict__ bqkv) {
    int bid = blockIdx.x, t = threadIdx.x;
    const float* src; bf16_t* dst; int idx;
    if (bid < 8192)       { src = batch; dst = Xb;             idx = bid * 256 + t; }
    else if (bid < 9216)  { src = wq;    dst = Wqkv;           idx = (bid - 8192) * 256 + t; }
    else if (bid < 10240) { src = wk;    dst = Wqkv + 1048576; idx = (bid - 9216) * 256 + t; }
    else if (bid < 11264) { src = wv;    dst = Wqkv + 2097152; idx = (bid - 10240) * 256 + t; }
    else if (bid < 12288) { src = wo;    dst = Wob;            idx = (bid - 11264) * 256 + t; }
    else {
        int i = (bid - 12288) * 256 + t;   // 0..3071
        if (i < 1024) bqkv[i] = bq[i];
        else if (i < 2048) bqkv[i] = bk[i - 1024];
        else if (i < 3072) bqkv[i] = bv[i - 2048];
        return;
    }
    float4 f = ((const float4*)src)[idx];
    v4bf o;
    o[0] = (bf16_t)f.x; o[1] = (bf16_t)f.y; o[2] = (bf16_t)f.z; o[3] = (bf16_t)f.w;
    ((v4bf*)dst)[idx] = o;
}

// ---------------------------------------------------------------- GEMM  C = A * B^T (+bias) (+resid)
// global_load_lds staging, double-buffered LDS, ONE barrier per K-iter.
// Unpadded 128x32 tiles, XOR swizzle (row r: logical chunk c at phys c^((r>>1)&3)).
__global__ __launch_bounds__(256, 3) void k_gemm_bt(
    const bf16_t* __restrict__ A, const bf16_t* __restrict__ Bm,
    const float* __restrict__ bias, const float* __restrict__ resid,
    bf16_t* __restrict__ Cb, float* __restrict__ Cf,
    int M, int N, int K, int qcols, float qmul)
{
    __shared__ bf16_t As[2][128 * 32];
    __shared__ bf16_t Bs[2][128 * 32];

    int nTile = N >> 7;
    int m0 = (blockIdx.x / nTile) << 7;
    int n0 = (blockIdx.x % nTile) << 7;
    int t = threadIdx.x;
    int w = t >> 6, lane = t & 63, quad = lane >> 4, ln = lane & 15;
    int wm = (w >> 1) << 6, wn = (w & 1) << 6;

    int srow = lane >> 2;                               // 0..15
    int scol = ((lane & 3) ^ ((lane >> 3) & 3)) << 3;   // swizzled logical chunk *8
    const bf16_t* Ag0 = A  + (size_t)(m0 + w * 16 +      srow) * K + scol;
    const bf16_t* Ag1 = A  + (size_t)(m0 + w * 16 + 64 + srow) * K + scol;
    const bf16_t* Bg0 = Bm + (size_t)(n0 + w * 16 +      srow) * K + scol;
    const bf16_t* Bg1 = Bm + (size_t)(n0 + w * 16 + 64 + srow) * K + scol;
    int lo0 = (w * 16) * 32, lo1 = (w * 16 + 64) * 32;

    v4f acc[4][4];
#pragma unroll
    for (int i = 0; i < 4; i++)
#pragma unroll
        for (int j = 0; j < 4; j++) acc[i][j] = (v4f){0.f, 0.f, 0.f, 0.f};

    // prologue: tile 0 -> buf 0
    GLD16(Ag0, &As[0][lo0]);
    GLD16(Ag1, &As[0][lo1]);
    GLD16(Bg0, &Bs[0][lo0]);
    GLD16(Bg1, &Bs[0][lo1]);

    int sw = (ln >> 1) & 3;   // read-side swizzle
    int buf = 0;
    for (int k0 = 0; k0 < K; k0 += 32, buf ^= 1) {
        __syncthreads();   // vmcnt(0) drain covers tile-k0 loads (in flight since k0-32)
        if (k0 + 32 < K) {
            GLD16(Ag0 + k0 + 32, &As[buf ^ 1][lo0]);
            GLD16(Ag1 + k0 + 32, &As[buf ^ 1][lo1]);
            GLD16(Bg0 + k0 + 32, &Bs[buf ^ 1][lo0]);
            GLD16(Bg1 + k0 + 32, &Bs[buf ^ 1][lo1]);
        }
        v8bf af[4], bfr[4];
#pragma unroll
        for (int mt = 0; mt < 4; mt++)
            af[mt] = *(const v8bf*)&As[buf][(wm + mt * 16 + ln) * 32 + ((quad ^ sw) << 3)];
#pragma unroll
        for (int nt = 0; nt < 4; nt++)
            bfr[nt] = *(const v8bf*)&Bs[buf][(wn + nt * 16 + ln) * 32 + ((quad ^ sw) << 3)];
#pragma unroll
        for (int mt = 0; mt < 4; mt++)
#pragma unroll
            for (int nt = 0; nt < 4; nt++)
                acc[mt][nt] = __builtin_amdgcn_mfma_f32_16x16x32_bf16(af[mt], bfr[nt], acc[mt][nt], 0, 0, 0);
    }

#pragma unroll
    for (int mt = 0; mt < 4; mt++) {
#pragma unroll
        for (int r = 0; r < 4; r++) {
            int row = m0 + wm + mt * 16 + quad * 4 + r;
#pragma unroll
            for (int nt = 0; nt < 4; nt++) {
                int col = n0 + wn + nt * 16 + ln;
                float v = acc[mt][nt][r] + bias[col];
                if (Cf) Cf[(size_t)row * N + col] = v + resid[(size_t)row * N + col];
                else {
                    if (col < qcols) v *= qmul;
                    Cb[(size_t)row * N + col] = (bf16_t)v;
                }
            }
        }
    }
}

// ---------------------------------------------------------------- V transpose: qkv V-cols -> Vt[bh][d][s]
__global__ __launch_bounds__(256) void k_transpose_v(const bf16_t* __restrict__ qkv,
                                                     bf16_t* __restrict__ vt) {
    __shared__ bf16_t tile[64 * 72];
    int bid = blockIdx.x;
    int st = bid & 31, bh = bid >> 5, b = bh >> 4, h = bh & 15;
    int t = threadIdx.x;
    const bf16_t* src = qkv + (size_t)(b * SEQ + st * 64) * 3072 + 2048 + h * 64;
#pragma unroll
    for (int i = 0; i < 2; i++) {
        int c = t + i * 256, row = c >> 3, c8 = (c & 7) << 3;
        *(uint4*)&tile[row * 72 + c8] = *(const uint4*)(src + (size_t)row * 3072 + c8);
    }
    __syncthreads();
    bf16_t* dst = vt + (size_t)bh * DHEAD * SEQ + st * 64;
#pragma unroll
    for (int i = 0; i < 2; i++) {
        int c = t + i * 256, d = c >> 3, s8 = (c & 7) << 3;
        v8bf o;
#pragma unroll
        for (int j = 0; j < 8; j++) o[j] = tile[(s8 + j) * 72 + d];
        *(v8bf*)(dst + (size_t)d * SEQ + s8) = o;
    }
}

// ---------------------------------------------------------------- attention
// ROUND-8 STRUCTURE (the measured-best concurrency point): grid 1024 blocks
// (4/CU, zero tail), 256 thr, wave owns 32 q-rows (2 q-sets), LDS exactly
// 40 KB, launch_bounds(256,3) [VGPR cap 85; (256,4) caps at 64 -> spills;
// round-9's 2-blocks/CU variant lost the drain-hiding: 11% occupancy].
// + round-9's packed-P grafted in: QK keys permuted (n-tile nt, lane ln ->
// K row 4*ln+nt) so each lane's 4 probs are contiguous -> ONE ds_write_b64
// per r (was 16 scalar b16 per q-set). P layout: elem (m,s) at
// m*64 + (((s>>3)^(m&7))<<3) + (s&7): 4-round writes, 8-round b128 reads.
__global__ __launch_bounds__(256, 3) void k_attn(const bf16_t* __restrict__ qkv,
                                                 const bf16_t* __restrict__ vt,
                                                 bf16_t* __restrict__ attn) {
    __shared__ bf16_t Ks[2][64 * 64];
    __shared__ bf16_t Vs[2][64 * 64];
    __shared__ bf16_t Pl[4][16 * 64];

    int bid = blockIdx.x;
    int qt = bid & 15, bh = bid >> 4, b = bh >> 4, h = bh & 15;
    int t = threadIdx.x, w = t >> 6, lane = t & 63, quad = lane >> 4, ln = lane & 15;
    int q0 = qt * 128 + w * 32;

    v8bf qf[2][2];
#pragma unroll
    for (int qs = 0; qs < 2; qs++) {
        const bf16_t* Qp = qkv + (size_t)(b * SEQ + q0 + qs * 16 + ln) * 3072 + h * 64 + quad * 8;
        qf[qs][0] = *(const v8bf*)Qp;
        qf[qs][1] = *(const v8bf*)(Qp + 32);
    }

    // staging addresses: wave w instr i covers rows (w+4i)*8 .. +7
    int srow = lane >> 3;                        // 0..7
    int scol = ((lane & 7) ^ (lane >> 3)) << 3;  // swizzled logical chunk *8
    const bf16_t* Kg0 = qkv + (size_t)(b * SEQ + w * 8 +      srow) * 3072 + 1024 + h * 64 + scol;
    const bf16_t* Kg1 = qkv + (size_t)(b * SEQ + w * 8 + 32 + srow) * 3072 + 1024 + h * 64 + scol;
    const bf16_t* Vg0 = vt + (size_t)bh * DHEAD * SEQ + (size_t)(w * 8 +      srow) * SEQ + scol;
    const bf16_t* Vg1 = vt + (size_t)bh * DHEAD * SEQ + (size_t)(w * 8 + 32 + srow) * SEQ + scol;
    int ko0 = (w * 8) * 64, ko1 = (w * 8 + 32) * 64;

    bf16_t* Pw = &Pl[w][0];
    int swv = ln & 7;   // read-side swizzle for V rows

    v4f o[2][4];
#pragma unroll
    for (int qs = 0; qs < 2; qs++)
#pragma unroll
        for (int d = 0; d < 4; d++) o[qs][d] = (v4f){0.f, 0.f, 0.f, 0.f};
    float lsum[2][4] = {{0.f,0.f,0.f,0.f},{0.f,0.f,0.f,0.f}};

    // prologue: tile 0 -> buf 0
    GLD16(Kg0, &Ks[0][ko0]);
    GLD16(Kg1, &Ks[0][ko1]);
    GLD16(Vg0, &Vs[0][ko0]);
    GLD16(Vg1, &Vs[0][ko1]);

    int buf = 0;
    for (int kt = 0; kt < SEQ; kt += 64, buf ^= 1) {
        __syncthreads();   // vmcnt(0) drain covers tile-kt loads (issued last iter)
        if (kt + 64 < SEQ) {
            GLD16(Kg0 + (size_t)(kt + 64) * 3072, &Ks[buf ^ 1][ko0]);
            GLD16(Kg1 + (size_t)(kt + 64) * 3072, &Ks[buf ^ 1][ko1]);
            GLD16(Vg0 + kt + 64, &Vs[buf ^ 1][ko0]);
            GLD16(Vg1 + kt + 64, &Vs[buf ^ 1][ko1]);
        }

        // QK^T, keys permuted: n-tile nt, lane ln -> K row 4*ln+nt
        v4f s0[4], s1[4];
#pragma unroll
        for (int nt = 0; nt < 4; nt++) {
            int rr = 4 * ln + nt;
            int swr = rr & 7;
            v8bf kf0 = *(const v8bf*)&Ks[buf][rr * 64 + ((quad ^ swr) << 3)];
            v8bf kf1 = *(const v8bf*)&Ks[buf][rr * 64 + (((quad + 4) ^ swr) << 3)];
            s0[nt] = (v4f){0.f, 0.f, 0.f, 0.f};
            s1[nt] = (v4f){0.f, 0.f, 0.f, 0.f};
            s0[nt] = __builtin_amdgcn_mfma_f32_16x16x32_bf16(qf[0][0], kf0, s0[nt], 0, 0, 0);
            s0[nt] = __builtin_amdgcn_mfma_f32_16x16x32_bf16(qf[0][1], kf1, s0[nt], 0, 0, 0);
            s1[nt] = __builtin_amdgcn_mfma_f32_16x16x32_bf16(qf[1][0], kf0, s1[nt], 0, 0, 0);
            s1[nt] = __builtin_amdgcn_mfma_f32_16x16x32_bf16(qf[1][1], kf1, s1[nt], 0, 0, 0);
        }

        // V fragments (shared by both q-sets)
        v8bf vf[8];
#pragma unroll
        for (int d = 0; d < 4; d++) {
            vf[d * 2]     = *(const v8bf*)&Vs[buf][(d * 16 + ln) * 64 + ((quad ^ swv) << 3)];
            vf[d * 2 + 1] = *(const v8bf*)&Vs[buf][(d * 16 + ln) * 64 + (((quad + 4) ^ swv) << 3)];
        }

        // per q-set: exp2 + ONE packed b64 P-write per r -> PV (in-order DS
        // queue serializes each qs's reads after its writes)
#pragma unroll
        for (int qs = 0; qs < 2; qs++) {
            v4f* s = qs ? s1 : s0;
#pragma unroll
            for (int r = 0; r < 4; r++) {
                float p0 = __builtin_amdgcn_exp2f(s[0][r]);
                float p1 = __builtin_amdgcn_exp2f(s[1][r]);
                float p2 = __builtin_amdgcn_exp2f(s[2][r]);
                float p3 = __builtin_amdgcn_exp2f(s[3][r]);
                int m = quad * 4 + r;
                v4bf pk;
                pk[0] = (bf16_t)p0; pk[1] = (bf16_t)p1;
                pk[2] = (bf16_t)p2; pk[3] = (bf16_t)p3;
                *(v4bf*)&Pw[m * 64 + (((ln >> 1) ^ (m & 7)) << 3) + ((ln & 1) << 2)] = pk;
                lsum[qs][r] += (p0 + p1) + (p2 + p3);
            }
#pragma unroll
            for (int tk = 0; tk < 2; tk++) {
                v8bf pf = *(const v8bf*)&Pw[ln * 64 + (((tk * 4 + quad) ^ (ln & 7)) << 3)];
#pragma unroll
                for (int d = 0; d < 4; d++)
                    o[qs][d] = __builtin_amdgcn_mfma_f32_16x16x32_bf16(pf, vf[tk + d * 2], o[qs][d], 0, 0, 0);
            }
        }
    }

#pragma unroll
    for (int qs = 0; qs < 2; qs++)
#pragma unroll
        for (int r = 0; r < 4; r++) {
#pragma unroll
            for (int off = 1; off < 16; off <<= 1) lsum[qs][r] += __shfl_xor(lsum[qs][r], off);
        }

#pragma unroll
    for (int qs = 0; qs < 2; qs++) {
        int rowg = b * SEQ + q0 + qs * 16;
#pragma unroll
        for (int r = 0; r < 4; r++) {
            float inv = 1.f / lsum[qs][r];
#pragma unroll
            for (int d = 0; d < 4; d++)
                attn[(size_t)(rowg + quad * 4 + r) * D_MODEL + h * 64 + d * 16 + ln] =
                    (bf16_t)(o[qs][d][r] * inv);
        }
    }
}

// ---------------------------------------------------------------- LayerNorm (one row / block)
__global__ __launch_bounds__(256) void k_layernorm(const float* __restrict__ y,
                                                   const float* __restrict__ g,
                                                   const float* __restrict__ beta,
                                                   float* __restrict__ out) {
    __shared__ float rs[4], rq[4];
    int row = blockIdx.x, t = threadIdx.x;
    int w = t >> 6, lane = t & 63;
    float4 v = ((const float4*)(y + (size_t)row * D_MODEL))[t];
    float s = v.x + v.y + v.z + v.w;
    float q = v.x * v.x + v.y * v.y + v.z * v.z + v.w * v.w;
#pragma unroll
    for (int off = 1; off < 64; off <<= 1) {
        s += __shfl_xor(s, off);
        q += __shfl_xor(q, off);
    }
    if (lane == 0) { rs[w] = s; rq[w] = q; }
    __syncthreads();
    s = rs[0] + rs[1] + rs[2] + rs[3];
    q = rq[0] + rq[1] + rq[2] + rq[3];
    float mu = s * (1.f / D_MODEL);
    float var = q * (1.f / D_MODEL) - mu * mu;
    float rstd = rsqrtf(var + 1e-5f);
    float4 gg = ((const float4*)g)[t];
    float4 bb = ((const float4*)beta)[t];
    float4 o;
    o.x = (v.x - mu) * rstd * gg.x + bb.x;
    o.y = (v.y - mu) * rstd * gg.y + bb.y;
    o.z = (v.z - mu) * rstd * gg.z + bb.z;
    o.w = (v.w - mu) * rstd * gg.w + bb.w;
    ((float4*)(out + (size_t)row * D_MODEL))[t] = o;
}

// ---------------------------------------------------------------- launch
extern "C" void kernel_launch(void* const* d_in, const int* in_sizes, int n_in,
                              void* d_out, int out_size, void* d_ws, size_t ws_size,
                              hipStream_t stream) {
    const float* batch = (const float*)d_in[0];
    const float* wq = (const float*)d_in[1];
    const float* bq = (const float*)d_in[2];
    const float* wk = (const float*)d_in[3];
    const float* bk = (const float*)d_in[4];
    const float* wv = (const float*)d_in[5];
    const float* bv = (const float*)d_in[6];
    const float* wo = (const float*)d_in[7];
    const float* bo = (const float*)d_in[8];
    const float* ln_g = (const float*)d_in[9];
    const float* ln_b = (const float*)d_in[10];
    float* out = (float*)d_out;

    char* ws = (char*)d_ws;
    size_t offXb   = 0;                                          // bf16 X (later Vt)
    size_t offWqkv = offXb + (size_t)ROWS * D_MODEL * 2;
    size_t offWo   = offWqkv + (size_t)3072 * 1024 * 2;
    size_t offBias = offWo + (size_t)1024 * 1024 * 2;
    size_t offQKV  = offBias + 3072 * 4;                         // bf16 qkv (later fp32 y)
    size_t offAttn = offQKV + (size_t)ROWS * 3072 * 2;
    size_t total   = offAttn + (size_t)ROWS * D_MODEL * 2;       // = 92,286,976
    if (ws_size < total) return;

    bf16_t* Xb   = (bf16_t*)(ws + offXb);
    bf16_t* Vt   = (bf16_t*)(ws + offXb);
    bf16_t* Wqkv = (bf16_t*)(ws + offWqkv);
    bf16_t* Wob  = (bf16_t*)(ws + offWo);
    float*  bqkv = (float*)(ws + offBias);
    bf16_t* qkv  = (bf16_t*)(ws + offQKV);
    float*  y    = (float*)(ws + offQKV);
    bf16_t* attn = (bf16_t*)(ws + offAttn);

    const float SC = 0.125f * 1.44269504088896f;  // 1/sqrt(64) * log2(e), folded into Q

    k_prep<<<12300, 256, 0, stream>>>(batch, wq, wk, wv, wo, bq, bk, bv,
                                      Xb, Wqkv, Wob, bqkv);
    k_gemm_bt<<<64 * 24, 256, 0, stream>>>(Xb, Wqkv, bqkv, nullptr, qkv, nullptr,
                                           8192, 3072, 1024, 1024, SC);
    k_transpose_v<<<2048, 256, 0, stream>>>(qkv, Vt);
    k_attn<<<1024, 256, 0, stream>>>(qkv, Vt, attn);
    k_gemm_bt<<<64 * 8, 256, 0, stream>>>(attn, Wob, bo, batch, nullptr, y,
                                          8192, 1024, 1024, 0, 1.0f);
    k_layernorm<<<8192, 256, 0, stream>>>(y, ln_g, ln_b, out);
}

// Round 11
// 314.475 us; speedup vs baseline: 1.1466x; 1.0817x over previous
//
#include <hip/hip_runtime.h>

typedef __bf16 bf16_t;
typedef __bf16 v8bf __attribute__((ext_vector_type(8)));
typedef __bf16 v4bf __attribute__((ext_vector_type(4)));
typedef float  v4f  __attribute__((ext_vector_type(4)));

#define D_MODEL 1024
#define NHEAD   16
#define DHEAD   64
#define SEQ     2048
#define BATCH   4
#define ROWS    (BATCH*SEQ)   // 8192

// async global->LDS, 16B per lane; LDS dest = wave-uniform base + lane*16
#define GLD16(g, l) __builtin_amdgcn_global_load_lds( \
    (const __attribute__((address_space(1))) void*)(g), \
    (__attribute__((address_space(3))) void*)(l), 16, 0, 0)

// ---------------------------------------------------------------- fused prep (casts + bias pack)
__global__ __launch_bounds__(256) void k_prep(const float* __restrict__ batch,
                                              const float* __restrict__ wq,
                                              const float* __restrict__ wk,
                                              const float* __restrict__ wv,
                                              const float* __restrict__ wo,
                                              const float* __restrict__ bq,
                                              const float* __restrict__ bk,
                                              const float* __restrict__ bv,
                                              bf16_t* __restrict__ Xb,
                                              bf16_t* __restrict__ Wqkv,
                                              bf16_t* __restrict__ Wob,
                                              float* __restrict__ bqkv) {
    int bid = blockIdx.x, t = threadIdx.x;
    const float* src; bf16_t* dst; int idx;
    if (bid < 8192)       { src = batch; dst = Xb;             idx = bid * 256 + t; }
    else if (bid < 9216)  { src = wq;    dst = Wqkv;           idx = (bid - 8192) * 256 + t; }
    else if (bid < 10240) { src = wk;    dst = Wqkv + 1048576; idx = (bid - 9216) * 256 + t; }
    else if (bid < 11264) { src = wv;    dst = Wqkv + 2097152; idx = (bid - 10240) * 256 + t; }
    else if (bid < 12288) { src = wo;    dst = Wob;            idx = (bid - 11264) * 256 + t; }
    else {
        int i = (bid - 12288) * 256 + t;   // 0..3071
        if (i < 1024) bqkv[i] = bq[i];
        else if (i < 2048) bqkv[i] = bk[i - 1024];
        else if (i < 3072) bqkv[i] = bv[i - 2048];
        return;
    }
    float4 f = ((const float4*)src)[idx];
    v4bf o;
    o[0] = (bf16_t)f.x; o[1] = (bf16_t)f.y; o[2] = (bf16_t)f.z; o[3] = (bf16_t)f.w;
    ((v4bf*)dst)[idx] = o;
}

// ---------------------------------------------------------------- GEMM  C = A * B^T (+bias) (+resid)
// global_load_lds staging, double-buffered LDS, ONE barrier per K-iter.
// Unpadded 128x32 tiles, XOR swizzle (row r: logical chunk c at phys c^((r>>1)&3)).
__global__ __launch_bounds__(256, 3) void k_gemm_bt(
    const bf16_t* __restrict__ A, const bf16_t* __restrict__ Bm,
    const float* __restrict__ bias, const float* __restrict__ resid,
    bf16_t* __restrict__ Cb, float* __restrict__ Cf,
    int M, int N, int K, int qcols, float qmul)
{
    __shared__ bf16_t As[2][128 * 32];
    __shared__ bf16_t Bs[2][128 * 32];

    int nTile = N >> 7;
    int m0 = (blockIdx.x / nTile) << 7;
    int n0 = (blockIdx.x % nTile) << 7;
    int t = threadIdx.x;
    int w = t >> 6, lane = t & 63, quad = lane >> 4, ln = lane & 15;
    int wm = (w >> 1) << 6, wn = (w & 1) << 6;

    int srow = lane >> 2;                               // 0..15
    int scol = ((lane & 3) ^ ((lane >> 3) & 3)) << 3;   // swizzled logical chunk *8
    const bf16_t* Ag0 = A  + (size_t)(m0 + w * 16 +      srow) * K + scol;
    const bf16_t* Ag1 = A  + (size_t)(m0 + w * 16 + 64 + srow) * K + scol;
    const bf16_t* Bg0 = Bm + (size_t)(n0 + w * 16 +      srow) * K + scol;
    const bf16_t* Bg1 = Bm + (size_t)(n0 + w * 16 + 64 + srow) * K + scol;
    int lo0 = (w * 16) * 32, lo1 = (w * 16 + 64) * 32;

    v4f acc[4][4];
#pragma unroll
    for (int i = 0; i < 4; i++)
#pragma unroll
        for (int j = 0; j < 4; j++) acc[i][j] = (v4f){0.f, 0.f, 0.f, 0.f};

    // prologue: tile 0 -> buf 0
    GLD16(Ag0, &As[0][lo0]);
    GLD16(Ag1, &As[0][lo1]);
    GLD16(Bg0, &Bs[0][lo0]);
    GLD16(Bg1, &Bs[0][lo1]);

    int sw = (ln >> 1) & 3;   // read-side swizzle
    int buf = 0;
    for (int k0 = 0; k0 < K; k0 += 32, buf ^= 1) {
        __syncthreads();   // vmcnt(0) drain covers tile-k0 loads (in flight since k0-32)
        if (k0 + 32 < K) {
            GLD16(Ag0 + k0 + 32, &As[buf ^ 1][lo0]);
            GLD16(Ag1 + k0 + 32, &As[buf ^ 1][lo1]);
            GLD16(Bg0 + k0 + 32, &Bs[buf ^ 1][lo0]);
            GLD16(Bg1 + k0 + 32, &Bs[buf ^ 1][lo1]);
        }
        v8bf af[4], bfr[4];
#pragma unroll
        for (int mt = 0; mt < 4; mt++)
            af[mt] = *(const v8bf*)&As[buf][(wm + mt * 16 + ln) * 32 + ((quad ^ sw) << 3)];
#pragma unroll
        for (int nt = 0; nt < 4; nt++)
            bfr[nt] = *(const v8bf*)&Bs[buf][(wn + nt * 16 + ln) * 32 + ((quad ^ sw) << 3)];
#pragma unroll
        for (int mt = 0; mt < 4; mt++)
#pragma unroll
            for (int nt = 0; nt < 4; nt++)
                acc[mt][nt] = __builtin_amdgcn_mfma_f32_16x16x32_bf16(af[mt], bfr[nt], acc[mt][nt], 0, 0, 0);
    }

#pragma unroll
    for (int mt = 0; mt < 4; mt++) {
#pragma unroll
        for (int r = 0; r < 4; r++) {
            int row = m0 + wm + mt * 16 + quad * 4 + r;
#pragma unroll
            for (int nt = 0; nt < 4; nt++) {
                int col = n0 + wn + nt * 16 + ln;
                float v = acc[mt][nt][r] + bias[col];
                if (Cf) Cf[(size_t)row * N + col] = v + resid[(size_t)row * N + col];
                else {
                    if (col < qcols) v *= qmul;
                    Cb[(size_t)row * N + col] = (bf16_t)v;
                }
            }
        }
    }
}

// ---------------------------------------------------------------- V transpose: qkv V-cols -> Vt[bh][d][s]
__global__ __launch_bounds__(256) void k_transpose_v(const bf16_t* __restrict__ qkv,
                                                     bf16_t* __restrict__ vt) {
    __shared__ bf16_t tile[64 * 72];
    int bid = blockIdx.x;
    int st = bid & 31, bh = bid >> 5, b = bh >> 4, h = bh & 15;
    int t = threadIdx.x;
    const bf16_t* src = qkv + (size_t)(b * SEQ + st * 64) * 3072 + 2048 + h * 64;
#pragma unroll
    for (int i = 0; i < 2; i++) {
        int c = t + i * 256, row = c >> 3, c8 = (c & 7) << 3;
        *(uint4*)&tile[row * 72 + c8] = *(const uint4*)(src + (size_t)row * 3072 + c8);
    }
    __syncthreads();
    bf16_t* dst = vt + (size_t)bh * DHEAD * SEQ + st * 64;
#pragma unroll
    for (int i = 0; i < 2; i++) {
        int c = t + i * 256, d = c >> 3, s8 = (c & 7) << 3;
        v8bf o;
#pragma unroll
        for (int j = 0; j < 8; j++) o[j] = tile[(s8 + j) * 72 + d];
        *(v8bf*)(dst + (size_t)d * SEQ + s8) = o;
    }
}

// ---------------------------------------------------------------- attention (register-resident P)
// grid 1024 blocks (4/CU, one full round), 256 thr, wave owns 32 q-rows.
// QK^T computed TRANSPOSED (S^T = K*Q^T: A=K-rows, B=Q) with a permuted
// key->tile map: tile nt covers keys 32(nt>>1)+8q+4(nt&1)+r, read via Ks row
// rr = 32(nt>>1)+4(nt&1)+8(ln>>2)+(ln&3). Result: lane(quad,ln) holds
// P[qrow=ln][keys tk*32+8*quad+j] = EXACTLY the PV A-fragment -> P never
// touches LDS (round-10: P round-trip was ~40% of LDS bank-time + 12.6M
// write conflicts + a write->read serial point). Denominator: 1 scalar/lane,
// reduced once (2 shfl_xor) + 4 shfl transpose in the epilogue.
// LDS 32 KB (K/V dbuf only); launch_bounds(256,2) caps VGPR at 128 (est
// ~115 live) -> 4 waves/SIMD -> 4 blocks/CU. Raw v_exp_f32 (scores O(3),
// Q pre-scaled by 0.125*log2e in GEMM1).
__global__ __launch_bounds__(256, 2) void k_attn(const bf16_t* __restrict__ qkv,
                                                 const bf16_t* __restrict__ vt,
                                                 bf16_t* __restrict__ attn) {
    __shared__ bf16_t Ks[2][64 * 64];
    __shared__ bf16_t Vs[2][64 * 64];

    int bid = blockIdx.x;
    int qt = bid & 15, bh = bid >> 4, b = bh >> 4, h = bh & 15;
    int t = threadIdx.x, w = t >> 6, lane = t & 63, quad = lane >> 4, ln = lane & 15;
    int q0 = qt * 128 + w * 32;

    v8bf qf[2][2];
#pragma unroll
    for (int qs = 0; qs < 2; qs++) {
        const bf16_t* Qp = qkv + (size_t)(b * SEQ + q0 + qs * 16 + ln) * 3072 + h * 64 + quad * 8;
        qf[qs][0] = *(const v8bf*)Qp;
        qf[qs][1] = *(const v8bf*)(Qp + 32);
    }

    // staging addresses: wave w instr i covers rows (w+4i)*8 .. +7
    int srow = lane >> 3;                        // 0..7
    int scol = ((lane & 7) ^ (lane >> 3)) << 3;  // swizzled logical chunk *8
    const bf16_t* Kg0 = qkv + (size_t)(b * SEQ + w * 8 +      srow) * 3072 + 1024 + h * 64 + scol;
    const bf16_t* Kg1 = qkv + (size_t)(b * SEQ + w * 8 + 32 + srow) * 3072 + 1024 + h * 64 + scol;
    const bf16_t* Vg0 = vt + (size_t)bh * DHEAD * SEQ + (size_t)(w * 8 +      srow) * SEQ + scol;
    const bf16_t* Vg1 = vt + (size_t)bh * DHEAD * SEQ + (size_t)(w * 8 + 32 + srow) * SEQ + scol;
    int ko0 = (w * 8) * 64, ko1 = (w * 8 + 32) * 64;

    int swv = ln & 7;                               // V-read swizzle (row&7 = ln&7)
    int rrbase = ((ln >> 2) << 3) + (ln & 3);       // 8*(ln>>2) + (ln&3)
    int o0 = (rrbase) * 64,       o1 = (rrbase + 4) * 64;        // nt 0 / 1 row offsets
    int o2 = (rrbase + 32) * 64,  o3 = (rrbase + 36) * 64;       // nt 2 / 3
    int sw0 = rrbase & 7, sw1 = (rrbase + 4) & 7;   // rr&7 for nt even / odd

    v4f o[2][4];
#pragma unroll
    for (int qs = 0; qs < 2; qs++)
#pragma unroll
        for (int d = 0; d < 4; d++) o[qs][d] = (v4f){0.f, 0.f, 0.f, 0.f};
    float lsum[2] = {0.f, 0.f};

    // prologue: tile 0 -> buf 0
    GLD16(Kg0, &Ks[0][ko0]);
    GLD16(Kg1, &Ks[0][ko1]);
    GLD16(Vg0, &Vs[0][ko0]);
    GLD16(Vg1, &Vs[0][ko1]);

    int buf = 0;
    for (int kt = 0; kt < SEQ; kt += 64, buf ^= 1) {
        __syncthreads();   // vmcnt(0) drain covers tile-kt loads (issued last iter)
        if (kt + 64 < SEQ) {
            GLD16(Kg0 + (size_t)(kt + 64) * 3072, &Ks[buf ^ 1][ko0]);
            GLD16(Kg1 + (size_t)(kt + 64) * 3072, &Ks[buf ^ 1][ko1]);
            GLD16(Vg0 + kt + 64, &Vs[buf ^ 1][ko0]);
            GLD16(Vg1 + kt + 64, &Vs[buf ^ 1][ko1]);
        }

        // S^T = K * Q^T; tile nt rows at permuted offsets (key map in header)
        const bf16_t* Kb = &Ks[buf][0];
        v4f s0[4], s1[4];
        int rof[4] = {o0, o1, o2, o3};
        int rsw[4] = {sw0, sw1, sw0, sw1};
#pragma unroll
        for (int nt = 0; nt < 4; nt++) {
            v8bf kf0 = *(const v8bf*)&Kb[rof[nt] + ((quad ^ rsw[nt]) << 3)];
            v8bf kf1 = *(const v8bf*)&Kb[rof[nt] + (((quad + 4) ^ rsw[nt]) << 3)];
            s0[nt] = (v4f){0.f, 0.f, 0.f, 0.f};
            s1[nt] = (v4f){0.f, 0.f, 0.f, 0.f};
            s0[nt] = __builtin_amdgcn_mfma_f32_16x16x32_bf16(kf0, qf[0][0], s0[nt], 0, 0, 0);
            s0[nt] = __builtin_amdgcn_mfma_f32_16x16x32_bf16(kf1, qf[0][1], s0[nt], 0, 0, 0);
            s1[nt] = __builtin_amdgcn_mfma_f32_16x16x32_bf16(kf0, qf[1][0], s1[nt], 0, 0, 0);
            s1[nt] = __builtin_amdgcn_mfma_f32_16x16x32_bf16(kf1, qf[1][1], s1[nt], 0, 0, 0);
        }

        // PV: P assembled in-register from s (lane's own values)
#pragma unroll
        for (int tk = 0; tk < 2; tk++) {
            v8bf vf0 = *(const v8bf*)&Vs[buf][(0 * 16 + ln) * 64 + (((tk * 4 + 0 + quad * 0) ^ 0) << 3)];
            // (dummy line removed below — real reads:)
            v8bf vfd[4];
#pragma unroll
            for (int d = 0; d < 4; d++)
                vfd[d] = *(const v8bf*)&Vs[buf][(d * 16 + ln) * 64 + (((tk * 4 + quad) ^ swv) << 3)];
            (void)vf0;
#pragma unroll
            for (int qs = 0; qs < 2; qs++) {
                v4f* s = qs ? s1 : s0;
                float e0 = __builtin_amdgcn_exp2f(s[2 * tk][0]);
                float e1 = __builtin_amdgcn_exp2f(s[2 * tk][1]);
                float e2 = __builtin_amdgcn_exp2f(s[2 * tk][2]);
                float e3 = __builtin_amdgcn_exp2f(s[2 * tk][3]);
                float e4 = __builtin_amdgcn_exp2f(s[2 * tk + 1][0]);
                float e5 = __builtin_amdgcn_exp2f(s[2 * tk + 1][1]);
                float e6 = __builtin_amdgcn_exp2f(s[2 * tk + 1][2]);
                float e7 = __builtin_amdgcn_exp2f(s[2 * tk + 1][3]);
                v8bf pf;
                pf[0] = (bf16_t)e0; pf[1] = (bf16_t)e1; pf[2] = (bf16_t)e2; pf[3] = (bf16_t)e3;
                pf[4] = (bf16_t)e4; pf[5] = (bf16_t)e5; pf[6] = (bf16_t)e6; pf[7] = (bf16_t)e7;
                lsum[qs] += ((e0 + e1) + (e2 + e3)) + ((e4 + e5) + (e6 + e7));
#pragma unroll
                for (int d = 0; d < 4; d++)
                    o[qs][d] = __builtin_amdgcn_mfma_f32_16x16x32_bf16(pf, vfd[d], o[qs][d], 0, 0, 0);
            }
        }
    }

    // denominator: reduce across the 4 quads holding qrow=ln, then transpose
#pragma unroll
    for (int qs = 0; qs < 2; qs++) {
        lsum[qs] += __shfl_xor(lsum[qs], 16);
        lsum[qs] += __shfl_xor(lsum[qs], 32);
    }

#pragma unroll
    for (int qs = 0; qs < 2; qs++) {
        int rowg = b * SEQ + q0 + qs * 16;
#pragma unroll
        for (int r = 0; r < 4; r++) {
            float inv = 1.f / __shfl(lsum[qs], 20 * quad + r);   // lane with ln = quad*4+r
#pragma unroll
            for (int d = 0; d < 4; d++)
                attn[(size_t)(rowg + quad * 4 + r) * D_MODEL + h * 64 + d * 16 + ln] =
                    (bf16_t)(o[qs][d][r] * inv);
        }
    }
}

// ---------------------------------------------------------------- LayerNorm (one row / block)
__global__ __launch_bounds__(256) void k_layernorm(const float* __restrict__ y,
                                                   const float* __restrict__ g,
                                                   const float* __restrict__ beta,
                                                   float* __restrict__ out) {
    __shared__ float rs[4], rq[4];
    int row = blockIdx.x, t = threadIdx.x;
    int w = t >> 6, lane = t & 63;
    float4 v = ((const float4*)(y + (size_t)row * D_MODEL))[t];
    float s = v.x + v.y + v.z + v.w;
    float q = v.x * v.x + v.y * v.y + v.z * v.z + v.w * v.w;
#pragma unroll
    for (int off = 1; off < 64; off <<= 1) {
        s += __shfl_xor(s, off);
        q += __shfl_xor(q, off);
    }
    if (lane == 0) { rs[w] = s; rq[w] = q; }
    __syncthreads();
    s = rs[0] + rs[1] + rs[2] + rs[3];
    q = rq[0] + rq[1] + rq[2] + rq[3];
    float mu = s * (1.f / D_MODEL);
    float var = q * (1.f / D_MODEL) - mu * mu;
    float rstd = rsqrtf(var + 1e-5f);
    float4 gg = ((const float4*)g)[t];
    float4 bb = ((const float4*)beta)[t];
    float4 o;
    o.x = (v.x - mu) * rstd * gg.x + bb.x;
    o.y = (v.y - mu) * rstd * gg.y + bb.y;
    o.z = (v.z - mu) * rstd * gg.z + bb.z;
    o.w = (v.w - mu) * rstd * gg.w + bb.w;
    ((float4*)(out + (size_t)row * D_MODEL))[t] = o;
}

// ---------------------------------------------------------------- launch
extern "C" void kernel_launch(void* const* d_in, const int* in_sizes, int n_in,
                              void* d_out, int out_size, void* d_ws, size_t ws_size,
                              hipStream_t stream) {
    const float* batch = (const float*)d_in[0];
    const float* wq = (const float*)d_in[1];
    const float* bq = (const float*)d_in[2];
    const float* wk = (const float*)d_in[3];
    const float* bk = (const float*)d_in[4];
    const float* wv = (const float*)d_in[5];
    const float* bv = (const float*)d_in[6];
    const float* wo = (const float*)d_in[7];
    const float* bo = (const float*)d_in[8];
    const float* ln_g = (const float*)d_in[9];
    const float* ln_b = (const float*)d_in[10];
    float* out = (float*)d_out;

    char* ws = (char*)d_ws;
    size_t offXb   = 0;                                          // bf16 X (later Vt)
    size_t offWqkv = offXb + (size_t)ROWS * D_MODEL * 2;
    size_t offWo   = offWqkv + (size_t)3072 * 1024 * 2;
    size_t offBias = offWo + (size_t)1024 * 1024 * 2;
    size_t offQKV  = offBias + 3072 * 4;                         // bf16 qkv (later fp32 y)
    size_t offAttn = offQKV + (size_t)ROWS * 3072 * 2;
    size_t total   = offAttn + (size_t)ROWS * D_MODEL * 2;       // = 92,286,976
    if (ws_size < total) return;

    bf16_t* Xb   = (bf16_t*)(ws + offXb);
    bf16_t* Vt   = (bf16_t*)(ws + offXb);
    bf16_t* Wqkv = (bf16_t*)(ws + offWqkv);
    bf16_t* Wob  = (bf16_t*)(ws + offWo);
    float*  bqkv = (float*)(ws + offBias);
    bf16_t* qkv  = (bf16_t*)(ws + offQKV);
    float*  y    = (float*)(ws + offQKV);
    bf16_t* attn = (bf16_t*)(ws + offAttn);

    const float SC = 0.125f * 1.44269504088896f;  // 1/sqrt(64) * log2(e), folded into Q

    k_prep<<<12300, 256, 0, stream>>>(batch, wq, wk, wv, wo, bq, bk, bv,
                                      Xb, Wqkv, Wob, bqkv);
    k_gemm_bt<<<64 * 24, 256, 0, stream>>>(Xb, Wqkv, bqkv, nullptr, qkv, nullptr,
                                           8192, 3072, 1024, 1024, SC);
    k_transpose_v<<<2048, 256, 0, stream>>>(qkv, Vt);
    k_attn<<<1024, 256, 0, stream>>>(qkv, Vt, attn);
    k_gemm_bt<<<64 * 8, 256, 0, stream>>>(attn, Wob, bo, batch, nullptr, y,
                                          8192, 1024, 1024, 0, 1.0f);
    k_layernorm<<<8192, 256, 0, stream>>>(y, ln_g, ln_b, out);
}

// Round 12
// 309.383 us; speedup vs baseline: 1.1655x; 1.0165x over previous
//
#include <hip/hip_runtime.h>

typedef __bf16 bf16_t;
typedef __bf16 v8bf __attribute__((ext_vector_type(8)));
typedef __bf16 v4bf __attribute__((ext_vector_type(4)));
typedef float  v4f  __attribute__((ext_vector_type(4)));

#define D_MODEL 1024
#define NHEAD   16
#define DHEAD   64
#define SEQ     2048
#define BATCH   4
#define ROWS    (BATCH*SEQ)   // 8192

// async global->LDS, 16B per lane; LDS dest = wave-uniform base + lane*16
#define GLD16(g, l) __builtin_amdgcn_global_load_lds( \
    (const __attribute__((address_space(1))) void*)(g), \
    (__attribute__((address_space(3))) void*)(l), 16, 0, 0)

// ---------------------------------------------------------------- fused prep (casts + bias pack)
__global__ __launch_bounds__(256) void k_prep(const float* __restrict__ batch,
                                              const float* __restrict__ wq,
                                              const float* __restrict__ wk,
                                              const float* __restrict__ wv,
                                              const float* __restrict__ wo,
                                              const float* __restrict__ bq,
                                              const float* __restrict__ bk,
                                              const float* __restrict__ bv,
                                              bf16_t* __restrict__ Xb,
                                              bf16_t* __restrict__ Wqkv,
                                              bf16_t* __restrict__ Wob,
                                              float* __restrict__ bqkv) {
    int bid = blockIdx.x, t = threadIdx.x;
    const float* src; bf16_t* dst; int idx;
    if (bid < 8192)       { src = batch; dst = Xb;             idx = bid * 256 + t; }
    else if (bid < 9216)  { src = wq;    dst = Wqkv;           idx = (bid - 8192) * 256 + t; }
    else if (bid < 10240) { src = wk;    dst = Wqkv + 1048576; idx = (bid - 9216) * 256 + t; }
    else if (bid < 11264) { src = wv;    dst = Wqkv + 2097152; idx = (bid - 10240) * 256 + t; }
    else if (bid < 12288) { src = wo;    dst = Wob;            idx = (bid - 11264) * 256 + t; }
    else {
        int i = (bid - 12288) * 256 + t;   // 0..3071
        if (i < 1024) bqkv[i] = bq[i];
        else if (i < 2048) bqkv[i] = bk[i - 1024];
        else if (i < 3072) bqkv[i] = bv[i - 2048];
        return;
    }
    float4 f = ((const float4*)src)[idx];
    v4bf o;
    o[0] = (bf16_t)f.x; o[1] = (bf16_t)f.y; o[2] = (bf16_t)f.z; o[3] = (bf16_t)f.w;
    ((v4bf*)dst)[idx] = o;
}

// ---------------------------------------------------------------- GEMM  C = A * B^T (+bias) (+resid)
// global_load_lds staging, double-buffered LDS, ONE barrier per K-iter.
// Unpadded 128x32 tiles, XOR swizzle (row r: logical chunk c at phys c^((r>>1)&3)).
// XCD-aware block swizzle: all n-blocks of one m-tile land on one XCD
// (xcd = m_idx & 7, assuming HW round-robins blockIdx % 8) -> per-XCD A
// working set = 8 m-tiles x 256 KB = 2 MB, fits the 4 MB XCD L2.
// Requires (M/128) % 8 == 0.
__global__ __launch_bounds__(256, 3) void k_gemm_bt(
    const bf16_t* __restrict__ A, const bf16_t* __restrict__ Bm,
    const float* __restrict__ bias, const float* __restrict__ resid,
    bf16_t* __restrict__ Cb, float* __restrict__ Cf,
    int M, int N, int K, int qcols, float qmul)
{
    __shared__ bf16_t As[2][128 * 32];
    __shared__ bf16_t Bs[2][128 * 32];

    int nTile = N >> 7;
    int x = blockIdx.x & 7, g = blockIdx.x >> 3;
    int n_idx = g % nTile;
    int m_idx = (g / nTile) * 8 + x;
    int m0 = m_idx << 7;
    int n0 = n_idx << 7;
    int t = threadIdx.x;
    int w = t >> 6, lane = t & 63, quad = lane >> 4, ln = lane & 15;
    int wm = (w >> 1) << 6, wn = (w & 1) << 6;

    int srow = lane >> 2;                               // 0..15
    int scol = ((lane & 3) ^ ((lane >> 3) & 3)) << 3;   // swizzled logical chunk *8
    const bf16_t* Ag0 = A  + (size_t)(m0 + w * 16 +      srow) * K + scol;
    const bf16_t* Ag1 = A  + (size_t)(m0 + w * 16 + 64 + srow) * K + scol;
    const bf16_t* Bg0 = Bm + (size_t)(n0 + w * 16 +      srow) * K + scol;
    const bf16_t* Bg1 = Bm + (size_t)(n0 + w * 16 + 64 + srow) * K + scol;
    int lo0 = (w * 16) * 32, lo1 = (w * 16 + 64) * 32;

    v4f acc[4][4];
#pragma unroll
    for (int i = 0; i < 4; i++)
#pragma unroll
        for (int j = 0; j < 4; j++) acc[i][j] = (v4f){0.f, 0.f, 0.f, 0.f};

    // prologue: tile 0 -> buf 0
    GLD16(Ag0, &As[0][lo0]);
    GLD16(Ag1, &As[0][lo1]);
    GLD16(Bg0, &Bs[0][lo0]);
    GLD16(Bg1, &Bs[0][lo1]);

    int sw = (ln >> 1) & 3;   // read-side swizzle
    int buf = 0;
    for (int k0 = 0; k0 < K; k0 += 32, buf ^= 1) {
        __syncthreads();   // vmcnt(0) drain covers tile-k0 loads (in flight since k0-32)
        if (k0 + 32 < K) {
            GLD16(Ag0 + k0 + 32, &As[buf ^ 1][lo0]);
            GLD16(Ag1 + k0 + 32, &As[buf ^ 1][lo1]);
            GLD16(Bg0 + k0 + 32, &Bs[buf ^ 1][lo0]);
            GLD16(Bg1 + k0 + 32, &Bs[buf ^ 1][lo1]);
        }
        v8bf af[4], bfr[4];
#pragma unroll
        for (int mt = 0; mt < 4; mt++)
            af[mt] = *(const v8bf*)&As[buf][(wm + mt * 16 + ln) * 32 + ((quad ^ sw) << 3)];
#pragma unroll
        for (int nt = 0; nt < 4; nt++)
            bfr[nt] = *(const v8bf*)&Bs[buf][(wn + nt * 16 + ln) * 32 + ((quad ^ sw) << 3)];
#pragma unroll
        for (int mt = 0; mt < 4; mt++)
#pragma unroll
            for (int nt = 0; nt < 4; nt++)
                acc[mt][nt] = __builtin_amdgcn_mfma_f32_16x16x32_bf16(af[mt], bfr[nt], acc[mt][nt], 0, 0, 0);
    }

#pragma unroll
    for (int mt = 0; mt < 4; mt++) {
#pragma unroll
        for (int r = 0; r < 4; r++) {
            int row = m0 + wm + mt * 16 + quad * 4 + r;
#pragma unroll
            for (int nt = 0; nt < 4; nt++) {
                int col = n0 + wn + nt * 16 + ln;
                float v = acc[mt][nt][r] + bias[col];
                if (Cf) Cf[(size_t)row * N + col] = v + resid[(size_t)row * N + col];
                else {
                    if (col < qcols) v *= qmul;
                    Cb[(size_t)row * N + col] = (bf16_t)v;
                }
            }
        }
    }
}

// ---------------------------------------------------------------- V transpose: qkv V-cols -> Vt[bh][d][s]
__global__ __launch_bounds__(256) void k_transpose_v(const bf16_t* __restrict__ qkv,
                                                     bf16_t* __restrict__ vt) {
    __shared__ bf16_t tile[64 * 72];
    int bid = blockIdx.x;
    int st = bid & 31, bh = bid >> 5, b = bh >> 4, h = bh & 15;
    int t = threadIdx.x;
    const bf16_t* src = qkv + (size_t)(b * SEQ + st * 64) * 3072 + 2048 + h * 64;
#pragma unroll
    for (int i = 0; i < 2; i++) {
        int c = t + i * 256, row = c >> 3, c8 = (c & 7) << 3;
        *(uint4*)&tile[row * 72 + c8] = *(const uint4*)(src + (size_t)row * 3072 + c8);
    }
    __syncthreads();
    bf16_t* dst = vt + (size_t)bh * DHEAD * SEQ + st * 64;
#pragma unroll
    for (int i = 0; i < 2; i++) {
        int c = t + i * 256, d = c >> 3, s8 = (c & 7) << 3;
        v8bf o;
#pragma unroll
        for (int j = 0; j < 8; j++) o[j] = tile[(s8 + j) * 72 + d];
        *(v8bf*)(dst + (size_t)d * SEQ + s8) = o;
    }
}

// ---------------------------------------------------------------- attention (register-resident P)
// grid 1024 blocks (4/CU, one full round), 256 thr, wave owns 32 q-rows.
// XCD-aware swizzle: xcd = bh & 7 -> each XCD serves 8 bh x 16 qt = 128
// blocks (one residency round); K+V working set 8 x 512 KB = 4 MB = one
// XCD L2. Kills the ~3x redundant FETCH (139 MB vs ~48 ideal, round 11).
// S^T = K*Q^T with permuted key->tile map (tile nt covers keys
// 32(nt>>1)+8q+4(nt&1)+r via Ks row rr = 32(nt>>1)+4(nt&1)+8(ln>>2)+(ln&3)):
// lane(quad,ln) holds P[qrow=ln][keys tk*32+8*quad+j] = the PV A-fragment,
// so P never touches LDS. Denominator: 1 scalar/lane, reduced at the end.
__global__ __launch_bounds__(256, 2) void k_attn(const bf16_t* __restrict__ qkv,
                                                 const bf16_t* __restrict__ vt,
                                                 bf16_t* __restrict__ attn) {
    __shared__ bf16_t Ks[2][64 * 64];
    __shared__ bf16_t Vs[2][64 * 64];

    int bid = blockIdx.x;
    int xcd = bid & 7, g = bid >> 3;
    int qt = g & 15;
    int bh = ((g >> 4) << 3) | xcd;
    int b = bh >> 4, h = bh & 15;
    int t = threadIdx.x, w = t >> 6, lane = t & 63, quad = lane >> 4, ln = lane & 15;
    int q0 = qt * 128 + w * 32;

    v8bf qf[2][2];
#pragma unroll
    for (int qs = 0; qs < 2; qs++) {
        const bf16_t* Qp = qkv + (size_t)(b * SEQ + q0 + qs * 16 + ln) * 3072 + h * 64 + quad * 8;
        qf[qs][0] = *(const v8bf*)Qp;
        qf[qs][1] = *(const v8bf*)(Qp + 32);
    }

    // staging addresses: wave w instr i covers rows (w+4i)*8 .. +7
    int srow = lane >> 3;                        // 0..7
    int scol = ((lane & 7) ^ (lane >> 3)) << 3;  // swizzled logical chunk *8
    const bf16_t* Kg0 = qkv + (size_t)(b * SEQ + w * 8 +      srow) * 3072 + 1024 + h * 64 + scol;
    const bf16_t* Kg1 = qkv + (size_t)(b * SEQ + w * 8 + 32 + srow) * 3072 + 1024 + h * 64 + scol;
    const bf16_t* Vg0 = vt + (size_t)bh * DHEAD * SEQ + (size_t)(w * 8 +      srow) * SEQ + scol;
    const bf16_t* Vg1 = vt + (size_t)bh * DHEAD * SEQ + (size_t)(w * 8 + 32 + srow) * SEQ + scol;
    int ko0 = (w * 8) * 64, ko1 = (w * 8 + 32) * 64;

    int swv = ln & 7;                               // V-read swizzle (row&7 = ln&7)
    int rrbase = ((ln >> 2) << 3) + (ln & 3);       // 8*(ln>>2) + (ln&3)
    int o0 = (rrbase) * 64,       o1 = (rrbase + 4) * 64;        // nt 0 / 1 row offsets
    int o2 = (rrbase + 32) * 64,  o3 = (rrbase + 36) * 64;       // nt 2 / 3
    int sw0 = rrbase & 7, sw1 = (rrbase + 4) & 7;   // rr&7 for nt even / odd

    v4f o[2][4];
#pragma unroll
    for (int qs = 0; qs < 2; qs++)
#pragma unroll
        for (int d = 0; d < 4; d++) o[qs][d] = (v4f){0.f, 0.f, 0.f, 0.f};
    float lsum[2] = {0.f, 0.f};

    // prologue: tile 0 -> buf 0
    GLD16(Kg0, &Ks[0][ko0]);
    GLD16(Kg1, &Ks[0][ko1]);
    GLD16(Vg0, &Vs[0][ko0]);
    GLD16(Vg1, &Vs[0][ko1]);

    int buf = 0;
    for (int kt = 0; kt < SEQ; kt += 64, buf ^= 1) {
        __syncthreads();   // vmcnt(0) drain covers tile-kt loads (issued last iter)
        if (kt + 64 < SEQ) {
            GLD16(Kg0 + (size_t)(kt + 64) * 3072, &Ks[buf ^ 1][ko0]);
            GLD16(Kg1 + (size_t)(kt + 64) * 3072, &Ks[buf ^ 1][ko1]);
            GLD16(Vg0 + kt + 64, &Vs[buf ^ 1][ko0]);
            GLD16(Vg1 + kt + 64, &Vs[buf ^ 1][ko1]);
        }

        // S^T = K * Q^T; tile nt rows at permuted offsets (key map in header)
        const bf16_t* Kb = &Ks[buf][0];
        v4f s0[4], s1[4];
        int rof[4] = {o0, o1, o2, o3};
        int rsw[4] = {sw0, sw1, sw0, sw1};
#pragma unroll
        for (int nt = 0; nt < 4; nt++) {
            v8bf kf0 = *(const v8bf*)&Kb[rof[nt] + ((quad ^ rsw[nt]) << 3)];
            v8bf kf1 = *(const v8bf*)&Kb[rof[nt] + (((quad + 4) ^ rsw[nt]) << 3)];
            s0[nt] = (v4f){0.f, 0.f, 0.f, 0.f};
            s1[nt] = (v4f){0.f, 0.f, 0.f, 0.f};
            s0[nt] = __builtin_amdgcn_mfma_f32_16x16x32_bf16(kf0, qf[0][0], s0[nt], 0, 0, 0);
            s0[nt] = __builtin_amdgcn_mfma_f32_16x16x32_bf16(kf1, qf[0][1], s0[nt], 0, 0, 0);
            s1[nt] = __builtin_amdgcn_mfma_f32_16x16x32_bf16(kf0, qf[1][0], s1[nt], 0, 0, 0);
            s1[nt] = __builtin_amdgcn_mfma_f32_16x16x32_bf16(kf1, qf[1][1], s1[nt], 0, 0, 0);
        }

        // PV: P assembled in-register from s (lane's own values)
#pragma unroll
        for (int tk = 0; tk < 2; tk++) {
            v8bf vfd[4];
#pragma unroll
            for (int d = 0; d < 4; d++)
                vfd[d] = *(const v8bf*)&Vs[buf][(d * 16 + ln) * 64 + (((tk * 4 + quad) ^ swv) << 3)];
#pragma unroll
            for (int qs = 0; qs < 2; qs++) {
                v4f* s = qs ? s1 : s0;
                float e0 = __builtin_amdgcn_exp2f(s[2 * tk][0]);
                float e1 = __builtin_amdgcn_exp2f(s[2 * tk][1]);
                float e2 = __builtin_amdgcn_exp2f(s[2 * tk][2]);
                float e3 = __builtin_amdgcn_exp2f(s[2 * tk][3]);
                float e4 = __builtin_amdgcn_exp2f(s[2 * tk + 1][0]);
                float e5 = __builtin_amdgcn_exp2f(s[2 * tk + 1][1]);
                float e6 = __builtin_amdgcn_exp2f(s[2 * tk + 1][2]);
                float e7 = __builtin_amdgcn_exp2f(s[2 * tk + 1][3]);
                v8bf pf;
                pf[0] = (bf16_t)e0; pf[1] = (bf16_t)e1; pf[2] = (bf16_t)e2; pf[3] = (bf16_t)e3;
                pf[4] = (bf16_t)e4; pf[5] = (bf16_t)e5; pf[6] = (bf16_t)e6; pf[7] = (bf16_t)e7;
                lsum[qs] += ((e0 + e1) + (e2 + e3)) + ((e4 + e5) + (e6 + e7));
#pragma unroll
                for (int d = 0; d < 4; d++)
                    o[qs][d] = __builtin_amdgcn_mfma_f32_16x16x32_bf16(pf, vfd[d], o[qs][d], 0, 0, 0);
            }
        }
    }

    // denominator: reduce across the 4 quads holding qrow=ln, then transpose
#pragma unroll
    for (int qs = 0; qs < 2; qs++) {
        lsum[qs] += __shfl_xor(lsum[qs], 16);
        lsum[qs] += __shfl_xor(lsum[qs], 32);
    }

#pragma unroll
    for (int qs = 0; qs < 2; qs++) {
        int rowg = b * SEQ + q0 + qs * 16;
#pragma unroll
        for (int r = 0; r < 4; r++) {
            float inv = 1.f / __shfl(lsum[qs], 20 * quad + r);   // lane with ln = quad*4+r
#pragma unroll
            for (int d = 0; d < 4; d++)
                attn[(size_t)(rowg + quad * 4 + r) * D_MODEL + h * 64 + d * 16 + ln] =
                    (bf16_t)(o[qs][d][r] * inv);
        }
    }
}

// ---------------------------------------------------------------- LayerNorm (one row / block)
__global__ __launch_bounds__(256) void k_layernorm(const float* __restrict__ y,
                                                   const float* __restrict__ g,
                                                   const float* __restrict__ beta,
                                                   float* __restrict__ out) {
    __shared__ float rs[4], rq[4];
    int row = blockIdx.x, t = threadIdx.x;
    int w = t >> 6, lane = t & 63;
    float4 v = ((const float4*)(y + (size_t)row * D_MODEL))[t];
    float s = v.x + v.y + v.z + v.w;
    float q = v.x * v.x + v.y * v.y + v.z * v.z + v.w * v.w;
#pragma unroll
    for (int off = 1; off < 64; off <<= 1) {
        s += __shfl_xor(s, off);
        q += __shfl_xor(q, off);
    }
    if (lane == 0) { rs[w] = s; rq[w] = q; }
    __syncthreads();
    s = rs[0] + rs[1] + rs[2] + rs[3];
    q = rq[0] + rq[1] + rq[2] + rq[3];
    float mu = s * (1.f / D_MODEL);
    float var = q * (1.f / D_MODEL) - mu * mu;
    float rstd = rsqrtf(var + 1e-5f);
    float4 gg = ((const float4*)g)[t];
    float4 bb = ((const float4*)beta)[t];
    float4 o;
    o.x = (v.x - mu) * rstd * gg.x + bb.x;
    o.y = (v.y - mu) * rstd * gg.y + bb.y;
    o.z = (v.z - mu) * rstd * gg.z + bb.z;
    o.w = (v.w - mu) * rstd * gg.w + bb.w;
    ((float4*)(out + (size_t)row * D_MODEL))[t] = o;
}

// ---------------------------------------------------------------- launch
extern "C" void kernel_launch(void* const* d_in, const int* in_sizes, int n_in,
                              void* d_out, int out_size, void* d_ws, size_t ws_size,
                              hipStream_t stream) {
    const float* batch = (const float*)d_in[0];
    const float* wq = (const float*)d_in[1];
    const float* bq = (const float*)d_in[2];
    const float* wk = (const float*)d_in[3];
    const float* bk = (const float*)d_in[4];
    const float* wv = (const float*)d_in[5];
    const float* bv = (const float*)d_in[6];
    const float* wo = (const float*)d_in[7];
    const float* bo = (const float*)d_in[8];
    const float* ln_g = (const float*)d_in[9];
    const float* ln_b = (const float*)d_in[10];
    float* out = (float*)d_out;

    char* ws = (char*)d_ws;
    size_t offXb   = 0;                                          // bf16 X (later Vt)
    size_t offWqkv = offXb + (size_t)ROWS * D_MODEL * 2;
    size_t offWo   = offWqkv + (size_t)3072 * 1024 * 2;
    size_t offBias = offWo + (size_t)1024 * 1024 * 2;
    size_t offQKV  = offBias + 3072 * 4;                         // bf16 qkv (later fp32 y)
    size_t offAttn = offQKV + (size_t)ROWS * 3072 * 2;
    size_t total   = offAttn + (size_t)ROWS * D_MODEL * 2;       // = 92,286,976
    if (ws_size < total) return;

    bf16_t* Xb   = (bf16_t*)(ws + offXb);
    bf16_t* Vt   = (bf16_t*)(ws + offXb);
    bf16_t* Wqkv = (bf16_t*)(ws + offWqkv);
    bf16_t* Wob  = (bf16_t*)(ws + offWo);
    float*  bqkv = (float*)(ws + offBias);
    bf16_t* qkv  = (bf16_t*)(ws + offQKV);
    float*  y    = (float*)(ws + offQKV);
    bf16_t* attn = (bf16_t*)(ws + offAttn);

    const float SC = 0.125f * 1.44269504088896f;  // 1/sqrt(64) * log2(e), folded into Q

    k_prep<<<12300, 256, 0, stream>>>(batch, wq, wk, wv, wo, bq, bk, bv,
                                      Xb, Wqkv, Wob, bqkv);
    k_gemm_bt<<<64 * 24, 256, 0, stream>>>(Xb, Wqkv, bqkv, nullptr, qkv, nullptr,
                                           8192, 3072, 1024, 1024, SC);
    k_transpose_v<<<2048, 256, 0, stream>>>(qkv, Vt);
    k_attn<<<1024, 256, 0, stream>>>(qkv, Vt, attn);
    k_gemm_bt<<<64 * 8, 256, 0, stream>>>(attn, Wob, bo, batch, nullptr, y,
                                          8192, 1024, 1024, 0, 1.0f);
    k_layernorm<<<8192, 256, 0, stream>>>(y, ln_g, ln_b, out);
}